// Round 9
// baseline (153.095 us; speedup 1.0000x reference)
//
#include <hip/hip_runtime.h>
#include <hip/hip_bf16.h>

// GCN layer: out = (D^-1/2 A D^-1/2 X) W^T + b
// Round 19 = R18 (verified best, 148.2us) + two latency-hiding fixes:
//   k_bin: binning blocks 2048 -> 1024 edges (391 -> 782 blocks). Binning
//     is latency-serial per block at ~1.5 blocks/CU; halving the per-block
//     chain halves its wall time (all 782 still co-resident: 6328 waves).
//     Per-(bin,shard) load ~131 << SUBCAP 224; reservation depth ~25 (= R13's
//     proven-free 24).
//   k_fused: 2-row interleaved gather. The dynamic j-loop blocked compiler
//     pipelining across rows (16 loads in flight max). Fusing rows (2i,2i+1)
//     into one j-loop over max(da,db) with wave-uniform guards issues both
//     16-load batches before either fmac block -> 32 loads in flight,
//     counted-vmcnt overlap of A-fmacs with B-loads (L3 gather is the
//     bottleneck: FETCH 77.8MB = L2-fill re-reads of the 12.85MB xs).
//
// ws: gbin[196*32] 25KB | pairs[196*32*224 u32] 5.6MB | dis[nrows f32]
//     200KB | degc[N] 50KB | ell[nrows*64 u16] 6.42MB | xs 12.85MB |
//     wb 32KB  ~= 25.2 MB (< 26 MB proven)

typedef short v8s __attribute__((ext_vector_type(8)));
typedef float v4f __attribute__((ext_vector_type(4)));

#define ELLCAP 64     // deg ~ Poisson(16); P(deg>64) ~ 1e-19/node. Guarded.
#define NSHARD 32     // reservation shards per bin (depth ~782/32 ~= 25)
#define SUBCAP 224    // per (bin,shard) ~ Poisson(131); +8 sigma. Guarded.
#define ROWSTRIDE 136 // 128 bf16 + 8 pad shorts; 272 B rows (16B-aligned)
#define EPB 1024      // edges per binning block (4 per thread)

static __device__ __forceinline__ unsigned int f2bf(float f) {
    __hip_bfloat16 h = __float2bfloat16(f);  // RNE
    return (unsigned int)__builtin_bit_cast(unsigned short, h);
}

// k_bin: blocks [0,16): W cast. [16,16+ncast): xs cast (4096 dwords each).
// Rest: 1024 edges each; LDS hist -> sharded reservation (overlapped with
// LDS local-offset pass) -> packed (localrow,col) scatter.
__global__ __launch_bounds__(256) void k_bin(
    const int* __restrict__ idx, int* __restrict__ gbin,
    unsigned int* __restrict__ pairs, const float4* __restrict__ w4,
    ushort4* __restrict__ wb4, const float2* __restrict__ x2,
    unsigned int* __restrict__ xs32, int E, int ncast, int N, int nbins) {
    int b = blockIdx.x;
    const int t = threadIdx.x;
    if (b < 16) {  // W cast: 16 blocks x 256 thr = 4096 float4s
        int i = b * 256 + t;
        float4 v = w4[i];
        ushort4 o;
        o.x = (unsigned short)f2bf(v.x);
        o.y = (unsigned short)f2bf(v.y);
        o.z = (unsigned short)f2bf(v.z);
        o.w = (unsigned short)f2bf(v.w);
        wb4[i] = o;
        return;
    }
    b -= 16;
    if (b < ncast) {  // xs cast: 4096 dwords (64 rows) per block, unscaled
        int base = b * 4096;
#pragma unroll 4
        for (int it = 0; it < 16; ++it) {
            int i = base + it * 256 + t;
            int lr = i >> 6;  // global row
            unsigned ov = 0u;
            if (lr < N) {
                float2 v = x2[i];
                ov = f2bf(v.x) | (f2bf(v.y) << 16);
            }
            xs32[i] = ov;  // rows >= N (incl. pad row N) -> zeros
        }
        return;
    }
    b -= ncast;
    __shared__ int hist[256];
    __shared__ int hist2[256];
    __shared__ int base[256];
    hist[t] = 0;
    hist2[t] = 0;
    __syncthreads();

    int e0 = b * EPB + t * 4;
    int nv = E - e0;
    nv = nv > 4 ? 4 : (nv < 0 ? 0 : nv);
    int rows[4], cols[4];
    if (nv == 4) {
        int4 a0 = *(const int4*)&idx[e0];
        int4 c0 = *(const int4*)&idx[E + e0];
        rows[0] = a0.x; rows[1] = a0.y; rows[2] = a0.z; rows[3] = a0.w;
        cols[0] = c0.x; cols[1] = c0.y; cols[2] = c0.z; cols[3] = c0.w;
    } else {
        for (int k = 0; k < 4; ++k) {
            rows[k] = (k < nv) ? idx[e0 + k] : 0;
            cols[k] = (k < nv) ? idx[E + e0 + k] : 0;
        }
    }
#pragma unroll
    for (int k = 0; k < 4; ++k)
        if (k < nv) atomicAdd(&hist[rows[k] >> 8], 1);
    __syncthreads();
    const int shard = b & (NSHARD - 1);
    if (t < nbins)  // ~25-deep contention; returns while hist2 pass runs
        base[t] = atomicAdd(&gbin[t * NSHARD + shard], hist[t]);
    // overlap: per-edge local offsets via LDS while reservations in flight
    int loc[4];
#pragma unroll
    for (int k = 0; k < 4; ++k)
        loc[k] = (k < nv) ? atomicAdd(&hist2[rows[k] >> 8], 1) : 0;
    __syncthreads();
#pragma unroll
    for (int k = 0; k < 4; ++k) {
        if (k < nv) {
            int bin = rows[k] >> 8;
            int pos = base[bin] + loc[k];
            if (pos < SUBCAP)
                pairs[((size_t)bin * NSHARD + shard) * SUBCAP + pos] =
                    (unsigned)(((rows[k] & 255) << 16) | cols[k]);
        }
    }
}

// k_ell: one block per bin, 1024 thr = 32 groups x 32 lanes; group g scans
// sub-region g (coalesced), LDS ELL build via LDS atomics, 32KB coalesced
// dump, dis = rsqrt(true deg) (0 for deg==0 / rows >= N), degc = min(d,64).
__global__ __launch_bounds__(1024) void k_ell(
    const unsigned int* __restrict__ pairs, const int* __restrict__ gbin,
    unsigned short* __restrict__ ell, unsigned char* __restrict__ degc,
    float* __restrict__ dis, int N) {
    __shared__ __align__(16) unsigned short lell[256 * ELLCAP];  // 32 KB
    __shared__ int cnt[256];
    const int bin = blockIdx.x;
    const int t = threadIdx.x;
    if (t < 256) cnt[t] = 0;
    __syncthreads();

    {
        const int g = t >> 5, l32 = t & 31;  // group g owns sub-region g
        int m = gbin[bin * NSHARD + g];
        m = m > SUBCAP ? SUBCAP : m;
        size_t pb = ((size_t)bin * NSHARD + g) * SUBCAP;
        for (int i = l32; i < m; i += 32) {
            unsigned pv = pairs[pb + i];
            int la = pv >> 16;
            int slot = atomicAdd(&cnt[la], 1);
            if (slot < ELLCAP)
                lell[la * ELLCAP + slot] = (unsigned short)(pv & 0xFFFF);
        }
    }
    __syncthreads();

    if (t < 256) {
        int r = bin * 256 + t;
        int d = cnt[t];
        if (r < N) {
            dis[r] = (d > 0) ? rsqrtf((float)d) : 0.f;
            degc[r] = (unsigned char)(d > ELLCAP ? ELLCAP : d);
        } else {
            dis[r] = 0.f;  // incl. pad row N
        }
    }

    // coalesced ELL dump: 32 KB = 8192 dwords into ell rows [bin*256,+256)
    // (ell sized nrows*ELLCAP; stale slots never read: guarded by degc).
    {
        unsigned int* gell = (unsigned int*)(ell + (size_t)bin * 256 * ELLCAP);
        const unsigned int* sell = (const unsigned int*)lell;
        for (int i = t; i < 8192; i += 1024) gell[i] = sell[i];
    }
}

// k_fused: 256 thr (4 waves), 32 rows/block, global ELL, no build phase.
// Prologue prefetch + 2-row interleaved gather (32 loads in flight).
__global__ __launch_bounds__(256) void k_fused(
    const unsigned short* __restrict__ ell, const unsigned char* __restrict__ degc,
    const float* __restrict__ dis, const unsigned int* __restrict__ xs32,
    const v8s* __restrict__ Wb8, const float* __restrict__ bias,
    float* __restrict__ out, int N) {
    __shared__ __align__(16) unsigned short smem[32 * ROWSTRIDE];
    const int nb0 = blockIdx.x * 32;
    const int wv = threadIdx.x >> 6, lane = threadIdx.x & 63;
    const int rowbase = nb0 + wv * 8;

    // prologue: independent loads for all 8 rows (no serial chains)
    int d8[8], c8[8];
    float dv8[8];
#pragma unroll
    for (int i = 0; i < 8; ++i) {
        int n = rowbase + i;
        int d = (n < N) ? degc[n] : 0;
        d8[i] = __builtin_amdgcn_readfirstlane(d);
        int cl = (n < N) ? ell[(size_t)n * ELLCAP + lane] : 0;
        c8[i] = (lane < d8[i]) ? cl : N;  // pad -> zero row, dis=0
    }
#pragma unroll
    for (int i = 0; i < 8; ++i) dv8[i] = dis[c8[i]];  // 8 independent gathers

#pragma unroll
    for (int ip = 0; ip < 4; ++ip) {
        const int ia = 2 * ip, ib = 2 * ip + 1;
        float a0 = 0.f, a1 = 0.f, b0 = 0.f, b1 = 0.f;
        const int da = d8[ia], db = d8[ib];
        const int ca = c8[ia], cb = c8[ib];
        const int dba = __builtin_bit_cast(int, dv8[ia]);
        const int dbb = __builtin_bit_cast(int, dv8[ib]);
        const int dmax = da > db ? da : db;
        for (int j = 0; j < dmax; j += 16) {  // uniform guards: scalar branch
            unsigned uua[16], uub[16];
            float sca[16], scb[16];
            const bool doA = j < da, doB = j < db;
            if (doA) {  // issue A batch (16 loads)
#pragma unroll
                for (int u = 0; u < 16; ++u) {
                    int cc = __builtin_amdgcn_readlane(ca, j + u);
                    uua[u] = xs32[(size_t)cc * 64 + lane];
                    sca[u] = __builtin_bit_cast(
                        float, __builtin_amdgcn_readlane(dba, j + u));
                }
            }
            if (doB) {  // issue B batch while A in flight
#pragma unroll
                for (int u = 0; u < 16; ++u) {
                    int cc = __builtin_amdgcn_readlane(cb, j + u);
                    uub[u] = xs32[(size_t)cc * 64 + lane];
                    scb[u] = __builtin_bit_cast(
                        float, __builtin_amdgcn_readlane(dbb, j + u));
                }
            }
            if (doA) {  // A fmacs overlap B's outstanding loads
#pragma unroll
                for (int u = 0; u < 16; ++u) {
                    a0 = fmaf(sca[u], __builtin_bit_cast(float, uua[u] << 16), a0);
                    a1 = fmaf(sca[u],
                              __builtin_bit_cast(float, uua[u] & 0xFFFF0000u), a1);
                }
            }
            if (doB) {
#pragma unroll
                for (int u = 0; u < 16; ++u) {
                    b0 = fmaf(scb[u], __builtin_bit_cast(float, uub[u] << 16), b0);
                    b1 = fmaf(scb[u],
                              __builtin_bit_cast(float, uub[u] & 0xFFFF0000u), b1);
                }
            }
        }
        float sA = dis[rowbase + ia];  // rows >= N read dis=0 (sized nrows)
        float sB = dis[rowbase + ib];
        a0 *= sA; a1 *= sA;
        b0 *= sB; b1 *= sB;
        unsigned pA = f2bf(a0) | (f2bf(a1) << 16);
        unsigned pB = f2bf(b0) | (f2bf(b1) << 16);
        *(unsigned int*)&smem[(size_t)(wv * 8 + ia) * ROWSTRIDE + lane * 2] = pA;
        *(unsigned int*)&smem[(size_t)(wv * 8 + ib) * ROWSTRIDE + lane * 2] = pB;
    }
    __syncthreads();

    // MFMA (R10-verified layout: A m=lane&15 k=quad*8+i; B row-major W bf16;
    // C/D col=lane&15 row=quad*4+reg). Wave: rows (wv&1)*16, cols (wv>>1)*64.
    {
        int quad = lane >> 4, m16 = lane & 15;
        int lrow = (wv & 1) * 16 + m16;
        v8s afrag[4];
#pragma unroll
        for (int kk = 0; kk < 4; ++kk)
            afrag[kk] = *(const v8s*)&smem[lrow * ROWSTRIDE + kk * 32 + quad * 8];
        int rbase = nb0 + (wv & 1) * 16 + quad * 4;
        int jbase = (wv >> 1) * 64;
#pragma unroll
        for (int jt = 0; jt < 4; ++jt) {
            int jcol = jbase + jt * 16 + m16;
            v4f acc = {0.f, 0.f, 0.f, 0.f};
#pragma unroll
            for (int kk = 0; kk < 4; ++kk) {
                v8s bfrag = Wb8[jcol * 16 + kk * 4 + quad];
                acc = __builtin_amdgcn_mfma_f32_16x16x32_bf16(afrag[kk], bfrag,
                                                              acc, 0, 0, 0);
            }
            float bj = bias[jcol];
#pragma unroll
            for (int r = 0; r < 4; ++r) {
                int row = rbase + r;
                if (row < N) out[(size_t)row * 128 + jcol] = acc[r] + bj;
            }
        }
    }
}

extern "C" void kernel_launch(void* const* d_in, const int* in_sizes, int n_in,
                              void* d_out, int out_size, void* d_ws, size_t ws_size,
                              hipStream_t stream) {
    const float* x = (const float*)d_in[0];
    const int* idx = (const int*)d_in[1];
    const float* W = (const float*)d_in[2];
    const float* b = (const float*)d_in[3];
    float* out = (float*)d_out;

    const int N = in_sizes[0] / 128;    // 50000
    const int E = in_sizes[1] / 2;      // 800000
    const int nbins = (N + 255) / 256;  // 196 (<= 256 required)
    const int nrows = nbins * 256;      // 50176 (covers pad row N)
    const int ncast = nbins * 4;        // 784 blocks x 4096 dwords = nrows*64

    char* p = (char*)d_ws;
    auto alloc = [&](size_t bytes) {
        char* r = p;
        p += (bytes + 63) & ~(size_t)63;
        return r;
    };
    int* gbin = (int*)alloc((size_t)nbins * NSHARD * 4);  // 25 KB
    unsigned int* pairs =
        (unsigned int*)alloc((size_t)nbins * NSHARD * SUBCAP * 4);  // 5.6 MB
    float* dis = (float*)alloc((size_t)nrows * 4);                  // 200 KB
    unsigned char* degc = (unsigned char*)alloc((size_t)N);         // 50 KB
    unsigned short* ell =
        (unsigned short*)alloc((size_t)nrows * ELLCAP * 2);  // 6.42 MB (nrows!)
    unsigned int* xs = (unsigned int*)alloc((size_t)nrows * 128 * 2);  // 12.85 MB
    ushort4* wb = (ushort4*)alloc(128 * 128 * 2);                      // 32 KB

    hipMemsetAsync(gbin, 0, (size_t)nbins * NSHARD * sizeof(int), stream);

    // 16 W-cast + 784 xs-cast + 782 binning blocks, all concurrent
    const int bblocks = 16 + ncast + (E + EPB - 1) / EPB;
    k_bin<<<bblocks, 256, 0, stream>>>(idx, gbin, pairs, (const float4*)W, wb,
                                       (const float2*)x, xs, E, ncast, N, nbins);
    k_ell<<<nbins, 1024, 0, stream>>>(pairs, gbin, ell, degc, dis, N);
    k_fused<<<(N + 31) / 32, 256, 0, stream>>>(ell, degc, dis, xs,
                                               (const v8s*)wb, b, out, N);
}

// Round 10
// 144.500 us; speedup vs baseline: 1.0595x; 1.0595x over previous
//
#include <hip/hip_runtime.h>
#include <hip/hip_bf16.h>

// GCN layer: out = (D^-1/2 A D^-1/2 X) W^T + b
// Round 20 = R18 (148.2us verified best) with stage-overlap restructure:
//   k_bin: BINNING ONLY (R18 binning verbatim, EPB 2048, 391 blocks).
//     The 38.5MB W/xs cast streaming is removed from this serial stage.
//   k_ell: mixed grid -- [0,196) ELL-build blocks (R18 k_ell verbatim),
//     [196,200) W-cast, [200,984) xs-cast (4096 dwords each). The cast
//     streaming overlaps the ELL blocks' latency-bound pairs scan (same
//     mixed-grid technique that k_bin used, moved to where it overlaps
//     instead of extending the binning stage).
//   k_fused: R18 VERBATIM (49.0us; R19 falsified the 2-row interleave --
//     compiler serialized batches, VGPR stayed 40). Gather is ~205MB
//     through L2/L3 at ~4.2TB/s; treated as near-floor.
//
// ws: gbin[196*32] 25KB | pairs[196*32*224 u32] 5.6MB | dis[nrows f32]
//     200KB | degc[N] 50KB | ell[nrows*64 u16] 6.42MB | xs 12.85MB |
//     wb 32KB  ~= 25.2 MB (< 26 MB proven)

typedef short v8s __attribute__((ext_vector_type(8)));
typedef float v4f __attribute__((ext_vector_type(4)));

#define ELLCAP 64     // deg ~ Poisson(16); P(deg>64) ~ 1e-19/node. Guarded.
#define NSHARD 32     // reservation shards per bin (depth ~391/32 ~= 12)
#define SUBCAP 224    // per (bin,shard) ~ Poisson(131); +8 sigma. Guarded.
#define ROWSTRIDE 136 // 128 bf16 + 8 pad shorts; 272 B rows (16B-aligned)
#define EPB 2048      // edges per binning block (8 per thread, R18-proven)

static __device__ __forceinline__ unsigned int f2bf(float f) {
    __hip_bfloat16 h = __float2bfloat16(f);  // RNE
    return (unsigned int)__builtin_bit_cast(unsigned short, h);
}

// k_bin: binning only. 2048 edges/block; LDS hist -> sharded reservation
// (overlapped with LDS local-offset pass) -> packed (localrow,col) scatter.
__global__ __launch_bounds__(256) void k_bin(
    const int* __restrict__ idx, int* __restrict__ gbin,
    unsigned int* __restrict__ pairs, int E, int nbins) {
    const int b = blockIdx.x;
    const int t = threadIdx.x;
    __shared__ int hist[256];
    __shared__ int hist2[256];
    __shared__ int base[256];
    hist[t] = 0;
    hist2[t] = 0;
    __syncthreads();

    int e0 = b * EPB + t * 8;
    int nv = E - e0;
    nv = nv > 8 ? 8 : (nv < 0 ? 0 : nv);
    int rows[8], cols[8];
    if (nv == 8) {
        int4 a0 = *(const int4*)&idx[e0];
        int4 a1 = *(const int4*)&idx[e0 + 4];
        int4 c0 = *(const int4*)&idx[E + e0];
        int4 c1 = *(const int4*)&idx[E + e0 + 4];
        rows[0] = a0.x; rows[1] = a0.y; rows[2] = a0.z; rows[3] = a0.w;
        rows[4] = a1.x; rows[5] = a1.y; rows[6] = a1.z; rows[7] = a1.w;
        cols[0] = c0.x; cols[1] = c0.y; cols[2] = c0.z; cols[3] = c0.w;
        cols[4] = c1.x; cols[5] = c1.y; cols[6] = c1.z; cols[7] = c1.w;
    } else {
        for (int k = 0; k < 8; ++k) {
            rows[k] = (k < nv) ? idx[e0 + k] : 0;
            cols[k] = (k < nv) ? idx[E + e0 + k] : 0;
        }
    }
#pragma unroll
    for (int k = 0; k < 8; ++k)
        if (k < nv) atomicAdd(&hist[rows[k] >> 8], 1);
    __syncthreads();
    const int shard = b & (NSHARD - 1);
    if (t < nbins)  // ~12-deep contention; returns while hist2 pass runs
        base[t] = atomicAdd(&gbin[t * NSHARD + shard], hist[t]);
    // overlap: per-edge local offsets via LDS while reservations in flight
    int loc[8];
#pragma unroll
    for (int k = 0; k < 8; ++k)
        loc[k] = (k < nv) ? atomicAdd(&hist2[rows[k] >> 8], 1) : 0;
    __syncthreads();
#pragma unroll
    for (int k = 0; k < 8; ++k) {
        if (k < nv) {
            int bin = rows[k] >> 8;
            int pos = base[bin] + loc[k];
            if (pos < SUBCAP)
                pairs[((size_t)bin * NSHARD + shard) * SUBCAP + pos] =
                    (unsigned)(((rows[k] & 255) << 16) | cols[k]);
        }
    }
}

// k_ell: mixed grid, 1024 thr.
//   blocks [0,nbins): ELL build (R18 verbatim): 32 groups x 32 lanes scan
//     sub-regions, LDS ELL, 32KB coalesced dump, dis/degc.
//   blocks [nbins,nbins+4): W cast (1024 float4 each).
//   blocks [nbins+4, nbins+4+ncast): xs cast, 4096 dwords each (4 iters).
__global__ __launch_bounds__(1024) void k_ell(
    const unsigned int* __restrict__ pairs, const int* __restrict__ gbin,
    unsigned short* __restrict__ ell, unsigned char* __restrict__ degc,
    float* __restrict__ dis, const float4* __restrict__ w4,
    ushort4* __restrict__ wb4, const float2* __restrict__ x2,
    unsigned int* __restrict__ xs32, int N, int nbins) {
    const int t = threadIdx.x;
    int b = blockIdx.x;
    if (b >= nbins) {
        b -= nbins;
        if (b < 4) {  // W cast: 4 blocks x 1024 thr = 4096 float4s
            int i = b * 1024 + t;
            float4 v = w4[i];
            ushort4 o;
            o.x = (unsigned short)f2bf(v.x);
            o.y = (unsigned short)f2bf(v.y);
            o.z = (unsigned short)f2bf(v.z);
            o.w = (unsigned short)f2bf(v.w);
            wb4[i] = o;
            return;
        }
        b -= 4;
        // xs cast: 4096 dwords (64 rows) per block, unscaled bf16
        int base = b * 4096;
#pragma unroll
        for (int it = 0; it < 4; ++it) {
            int i = base + it * 1024 + t;
            int lr = i >> 6;  // global row
            unsigned ov = 0u;
            if (lr < N) {
                float2 v = x2[i];
                ov = f2bf(v.x) | (f2bf(v.y) << 16);
            }
            xs32[i] = ov;  // rows >= N (incl. pad row N) -> zeros
        }
        return;
    }

    __shared__ __align__(16) unsigned short lell[256 * ELLCAP];  // 32 KB
    __shared__ int cnt[256];
    const int bin = b;
    if (t < 256) cnt[t] = 0;
    __syncthreads();

    {
        const int g = t >> 5, l32 = t & 31;  // group g owns sub-region g
        int m = gbin[bin * NSHARD + g];
        m = m > SUBCAP ? SUBCAP : m;
        size_t pb = ((size_t)bin * NSHARD + g) * SUBCAP;
        for (int i = l32; i < m; i += 32) {
            unsigned pv = pairs[pb + i];
            int la = pv >> 16;
            int slot = atomicAdd(&cnt[la], 1);
            if (slot < ELLCAP)
                lell[la * ELLCAP + slot] = (unsigned short)(pv & 0xFFFF);
        }
    }
    __syncthreads();

    if (t < 256) {
        int r = bin * 256 + t;
        int d = cnt[t];
        if (r < N) {
            dis[r] = (d > 0) ? rsqrtf((float)d) : 0.f;
            degc[r] = (unsigned char)(d > ELLCAP ? ELLCAP : d);
        } else {
            dis[r] = 0.f;  // incl. pad row N
        }
    }

    // coalesced ELL dump: 32 KB = 8192 dwords into ell rows [bin*256,+256)
    // (ell sized nrows*ELLCAP; stale slots never read: guarded by degc).
    {
        unsigned int* gell = (unsigned int*)(ell + (size_t)bin * 256 * ELLCAP);
        const unsigned int* sell = (const unsigned int*)lell;
        for (int i = t; i < 8192; i += 1024) gell[i] = sell[i];
    }
}

// k_fused (R18 VERBATIM): 256 thr (4 waves), 32 rows/block, global ELL.
// Prologue prefetch: all 8 rows' degc + ell row + per-lane dis[c] issued as
// independent loads. Then 16-wide readlane batches + verified MFMA.
__global__ __launch_bounds__(256) void k_fused(
    const unsigned short* __restrict__ ell, const unsigned char* __restrict__ degc,
    const float* __restrict__ dis, const unsigned int* __restrict__ xs32,
    const v8s* __restrict__ Wb8, const float* __restrict__ bias,
    float* __restrict__ out, int N) {
    __shared__ __align__(16) unsigned short smem[32 * ROWSTRIDE];
    const int nb0 = blockIdx.x * 32;
    const int wv = threadIdx.x >> 6, lane = threadIdx.x & 63;
    const int rowbase = nb0 + wv * 8;

    // prologue: independent loads for all 8 rows (no serial chains)
    int d8[8], c8[8];
    float dv8[8];
#pragma unroll
    for (int i = 0; i < 8; ++i) {
        int n = rowbase + i;
        int d = (n < N) ? degc[n] : 0;
        d8[i] = __builtin_amdgcn_readfirstlane(d);
        int cl = (n < N) ? ell[(size_t)n * ELLCAP + lane] : 0;
        c8[i] = (lane < d8[i]) ? cl : N;  // pad -> zero row, dis=0
    }
#pragma unroll
    for (int i = 0; i < 8; ++i) dv8[i] = dis[c8[i]];  // 8 independent gathers

#pragma unroll
    for (int i = 0; i < 8; ++i) {
        int n = rowbase + i;
        float acc0 = 0.f, acc1 = 0.f;
        int d = d8[i];
        int c = c8[i];
        int dcb = __builtin_bit_cast(int, dv8[i]);
        for (int j = 0; j < d; j += 16) {  // j in {0,16,32,48}
            int cc[16];
#pragma unroll
            for (int u = 0; u < 16; ++u)
                cc[u] = __builtin_amdgcn_readlane(c, j + u);
            unsigned uu[16];
#pragma unroll
            for (int u = 0; u < 16; ++u)
                uu[u] = xs32[(size_t)cc[u] * 64 + lane];
            float sc[16];
#pragma unroll
            for (int u = 0; u < 16; ++u)
                sc[u] = __builtin_bit_cast(float,
                                           __builtin_amdgcn_readlane(dcb, j + u));
#pragma unroll
            for (int u = 0; u < 16; ++u) {
                acc0 = fmaf(sc[u], __builtin_bit_cast(float, uu[u] << 16), acc0);
                acc1 = fmaf(sc[u],
                            __builtin_bit_cast(float, uu[u] & 0xFFFF0000u), acc1);
            }
        }
        float s = dis[n];  // rows >= N read dis=0 (sized nrows)
        acc0 *= s;
        acc1 *= s;
        unsigned pack = f2bf(acc0) | (f2bf(acc1) << 16);
        *(unsigned int*)&smem[(size_t)(wv * 8 + i) * ROWSTRIDE + lane * 2] = pack;
    }
    __syncthreads();

    // MFMA (R10-verified layout: A m=lane&15 k=quad*8+i; B row-major W bf16;
    // C/D col=lane&15 row=quad*4+reg). Wave: rows (wv&1)*16, cols (wv>>1)*64.
    {
        int quad = lane >> 4, m16 = lane & 15;
        int lrow = (wv & 1) * 16 + m16;
        v8s afrag[4];
#pragma unroll
        for (int kk = 0; kk < 4; ++kk)
            afrag[kk] = *(const v8s*)&smem[lrow * ROWSTRIDE + kk * 32 + quad * 8];
        int rbase = nb0 + (wv & 1) * 16 + quad * 4;
        int jbase = (wv >> 1) * 64;
#pragma unroll
        for (int jt = 0; jt < 4; ++jt) {
            int jcol = jbase + jt * 16 + m16;
            v4f acc = {0.f, 0.f, 0.f, 0.f};
#pragma unroll
            for (int kk = 0; kk < 4; ++kk) {
                v8s bfrag = Wb8[jcol * 16 + kk * 4 + quad];
                acc = __builtin_amdgcn_mfma_f32_16x16x32_bf16(afrag[kk], bfrag,
                                                              acc, 0, 0, 0);
            }
            float bj = bias[jcol];
#pragma unroll
            for (int r = 0; r < 4; ++r) {
                int row = rbase + r;
                if (row < N) out[(size_t)row * 128 + jcol] = acc[r] + bj;
            }
        }
    }
}

extern "C" void kernel_launch(void* const* d_in, const int* in_sizes, int n_in,
                              void* d_out, int out_size, void* d_ws, size_t ws_size,
                              hipStream_t stream) {
    const float* x = (const float*)d_in[0];
    const int* idx = (const int*)d_in[1];
    const float* W = (const float*)d_in[2];
    const float* b = (const float*)d_in[3];
    float* out = (float*)d_out;

    const int N = in_sizes[0] / 128;    // 50000
    const int E = in_sizes[1] / 2;      // 800000
    const int nbins = (N + 255) / 256;  // 196 (<= 256 required)
    const int nrows = nbins * 256;      // 50176 (covers pad row N)
    const int ncast = nrows / 64;       // 784 xs-cast blocks x 4096 dwords

    char* p = (char*)d_ws;
    auto alloc = [&](size_t bytes) {
        char* r = p;
        p += (bytes + 63) & ~(size_t)63;
        return r;
    };
    int* gbin = (int*)alloc((size_t)nbins * NSHARD * 4);  // 25 KB
    unsigned int* pairs =
        (unsigned int*)alloc((size_t)nbins * NSHARD * SUBCAP * 4);  // 5.6 MB
    float* dis = (float*)alloc((size_t)nrows * 4);                  // 200 KB
    unsigned char* degc = (unsigned char*)alloc((size_t)N);         // 50 KB
    unsigned short* ell =
        (unsigned short*)alloc((size_t)nrows * ELLCAP * 2);  // 6.42 MB (nrows!)
    unsigned int* xs = (unsigned int*)alloc((size_t)nrows * 128 * 2);  // 12.85 MB
    ushort4* wb = (ushort4*)alloc(128 * 128 * 2);                      // 32 KB

    hipMemsetAsync(gbin, 0, (size_t)nbins * NSHARD * sizeof(int), stream);

    const int bblocks = (E + EPB - 1) / EPB;  // 391, binning only
    k_bin<<<bblocks, 256, 0, stream>>>(idx, gbin, pairs, E, nbins);
    // 196 ELL + 4 W-cast + 784 xs-cast blocks, casts overlap the pairs scan
    k_ell<<<nbins + 4 + ncast, 1024, 0, stream>>>(pairs, gbin, ell, degc, dis,
                                                  (const float4*)W, wb,
                                                  (const float2*)x, xs, N, nbins);
    k_fused<<<(N + 31) / 32, 256, 0, stream>>>(ell, degc, dis, xs,
                                               (const v8s*)wb, b, out, N);
}